// Round 1
// baseline (236.058 us; speedup 1.0000x reference)
//
#include <hip/hip_runtime.h>
#include <cstdint>
#include <cstddef>

// Problem constants
#define BQ 8
#define CDIM 64
#define HQ 64
#define WQ 64
#define KDIM 512
#define N_SIG 32768   // B*H*W
#define S_NNZ 4

// d_out float offsets (outputs concatenated flat in return order)
#define DIFF_ENC_OFF 2097152
#define DIFF_DICT_OFF 2097153
#define IDS_OFF 2097154
#define NUM_STEPS_OFF 18874370
#define MEAN_D_OFF 18874371
#define MEAN_Z_OFF 18874372
#define NORM_Z_OFF 18874373
#define TOP_PCT_OFF 18874374
#define NUM_ZEROS_OFF 18874375

// ws float-offsets
// words [0..3]  : accs[2] doubles: sumAbsZ, sumSq (zeroed by k_g block 0)
// words [4..8]  : hist[5] ints                    (zeroed by k_g block 0)
// [16..24)      : pd[8] per-diagonal-block |Dn| partial sums
#define WS_PD 16
#define WS_DNT 24
#define WS_G 32792
#define WS_WG 294936   // float4 per signal (deduped gamma)
#define WS_WI 426008   // int4 per signal (idx)

// Interleaved normalized dictionary staged in d_out's ids region (written by
// k_g, consumed by k_fused, overwritten later by k_ei). Layout:
//   Dil[((c*2 + j)*64 + l)*4 + f] = Dn[c][l*8 + j*4 + f]
// so lane l reads its 8 atoms for row c as two contiguous b128s.
#define DIL_OFF 4194304

typedef float v2f __attribute__((ext_vector_type(2)));

// ---- Gram kernel: 64 blocks, G = Dn^T Dn (8x8 tiles of 64); diagonal blocks
// also emit DnT, Dil and pd. alpha0 is no longer materialized anywhere.
__global__ __launch_bounds__(256) void k_g(const float* __restrict__ D,
                                           float* __restrict__ G,
                                           float* __restrict__ DnT,
                                           float* __restrict__ pd,
                                           float* __restrict__ Dil,
                                           float* __restrict__ W) {
  __shared__ float Xs[64 * 64];
  __shared__ float Dns[64 * 64];
  __shared__ float partA[4][64];
  __shared__ float partB[4][64];
  __shared__ float invA[64];
  __shared__ float invB[64];
  int tid = threadIdx.x;
  int w = tid & 63, cq = tid >> 6;
  int ty = tid >> 4, tx = tid & 15;
  if (blockIdx.x == 0 && tid < 16) ((unsigned int*)W)[tid] = 0u;  // accs+hist zero

  int ti = (int)blockIdx.x >> 3, tj = (int)blockIdx.x & 7;
#pragma unroll
  for (int p = 0; p < 16; ++p) {
    int c = p * 4 + cq;
    Xs[c * 64 + w] = D[(size_t)c * KDIM + ti * 64 + w];
    Dns[c * 64 + w] = D[(size_t)c * KDIM + tj * 64 + w];
  }
  __syncthreads();
  float ssA = 0.f, ssB = 0.f;
#pragma unroll
  for (int cc = 0; cc < 16; ++cc) {
    int c = cq * 16 + cc;
    float a = Xs[c * 64 + w];
    ssA = fmaf(a, a, ssA);
    float bv = Dns[c * 64 + w];
    ssB = fmaf(bv, bv, ssB);
  }
  partA[cq][w] = ssA;
  partB[cq][w] = ssB;
  __syncthreads();
  if (tid < 64) {
    invA[tid] = 1.0f / sqrtf(partA[0][tid] + partA[1][tid] + partA[2][tid] + partA[3][tid]);
    invB[tid] = 1.0f / sqrtf(partB[0][tid] + partB[1][tid] + partB[2][tid] + partB[3][tid]);
  }
  __syncthreads();
  if (ti == tj) {
    // emit normalized DnT rows, interleaved Dil slice, pd[ti] = sum|Dn| partial
    int kl = tid >> 2, cp = (tid & 3) * 16;
    float ia = invA[kl];
    int kg = ti * 64 + kl;              // global atom index
    int il = kg >> 3, ij = (kg >> 2) & 1, iff = kg & 3;
    float sabs = 0.f;
#pragma unroll
    for (int i = 0; i < 16; ++i) {
      int c = cp + i;
      float v = Xs[c * 64 + kl] * ia;
      DnT[(size_t)kg * CDIM + c] = v;
      Dil[((c * 2 + ij) * 64 + il) * 4 + iff] = v;
      sabs += fabsf(v);
    }
#pragma unroll
    for (int off = 32; off >= 1; off >>= 1) sabs += __shfl_xor(sabs, off);
    __syncthreads();
    if ((tid & 63) == 0) partA[0][tid >> 6] = sabs;
    __syncthreads();
    if (tid == 0) pd[ti] = partA[0][0] + partA[0][1] + partA[0][2] + partA[0][3];
  }
  v2f acc[4][2] = {};
  for (int c = 0; c < 64; ++c) {
    float4 avv = *(const float4*)&Xs[c * 64 + ty * 4];
    float av[4] = {avv.x, avv.y, avv.z, avv.w};
    float4 bv = *(const float4*)&Dns[c * 64 + tx * 4];
    v2f b0 = {bv.x, bv.y}, b1 = {bv.z, bv.w};
#pragma unroll
    for (int i = 0; i < 4; ++i) {
      v2f a2 = {av[i], av[i]};
      acc[i][0] = __builtin_elementwise_fma(a2, b0, acc[i][0]);
      acc[i][1] = __builtin_elementwise_fma(a2, b1, acc[i][1]);
    }
  }
  float sn[4] = {invB[tx * 4], invB[tx * 4 + 1], invB[tx * 4 + 2], invB[tx * 4 + 3]};
#pragma unroll
  for (int i = 0; i < 4; ++i) {
    float im = invA[ty * 4 + i];
    float4 st = make_float4(acc[i][0].x * im * sn[0], acc[i][0].y * im * sn[1],
                            acc[i][1].x * im * sn[2], acc[i][1].y * im * sn[3]);
    *(float4*)&G[(size_t)(ti * 64 + ty * 4 + i) * KDIM + tj * 64 + tx * 4] = st;
  }
}

// ---- DPP wave-64 max of a non-negative float; returns wave-uniform (SGPR) value ----
__device__ __forceinline__ float wave_absmax_u(float m) {
#define DPP_MAX(ctrl)                                                              \
  {                                                                                \
    int t_ = __builtin_amdgcn_update_dpp(0, __float_as_int(m), (ctrl), 0xf, 0xf,   \
                                         true);                                    \
    m = fmaxf(m, __int_as_float(t_));                                              \
  }
  DPP_MAX(0x111) DPP_MAX(0x112) DPP_MAX(0x114) DPP_MAX(0x118)
  DPP_MAX(0x142) DPP_MAX(0x143)
#undef DPP_MAX
  return __int_as_float(__builtin_amdgcn_readlane(__float_as_int(m), 63));
}

// ---- fp32 solve, no pivoting (G_II near-identity), saved reciprocals ----
template <int SZ>
__device__ __forceinline__ void solve_sz(const float (&gs)[4][4], const float (&rhs)[4],
                                         float (&gamma)[4]) {
  float M[SZ][SZ];
  float y[SZ];
  float idg[SZ];
#pragma unroll
  for (int a = 0; a < SZ; ++a) {
    y[a] = rhs[a];
#pragma unroll
    for (int b = 0; b < SZ; ++b) M[a][b] = gs[a][b] + (a == b ? 1e-7f : 0.0f);
  }
#pragma unroll
  for (int p = 0; p < SZ; ++p) {
    float ip = __builtin_amdgcn_rcpf(M[p][p]);
    idg[p] = ip;
#pragma unroll
    for (int r = p + 1; r < SZ; ++r) {
      float f = M[r][p] * ip;
#pragma unroll
      for (int c = p + 1; c < SZ; ++c) M[r][c] = fmaf(-f, M[p][c], M[r][c]);
      y[r] = fmaf(-f, y[p], y[r]);
    }
  }
#pragma unroll
  for (int r = SZ - 1; r >= 0; --r) {
    float t = y[r];
#pragma unroll
    for (int c = r + 1; c < SZ; ++c) t = fmaf(-M[r][c], gamma[c], t);
    gamma[r] = t * idg[r];
  }
}

// ---- one OMP step, alpha fully in registers (lane l owns atoms l*8..l*8+8) ----
template <int K>
__device__ __forceinline__ void omp_step2(int lane, const float* __restrict__ G,
                                          const float (&a0)[8], float (&al)[8],
                                          float (&Grow)[3][8], float (&gs)[4][4],
                                          float (&rhs)[4], int (&idx)[4],
                                          float (&gamma)[4]) {
  // per-lane argmax with lowest-m tie-break (strict >)
  float mx0 = fabsf(al[0]);
  int mi = 0;
#pragma unroll
  for (int m = 1; m < 8; ++m) {
    float v = fabsf(al[m]);
    mi = (v > mx0) ? m : mi;
    mx0 = fmaxf(v, mx0);
  }
  float mx = wave_absmax_u(mx0);  // wave-uniform SGPR
  // single ballot; lowest lane wins; lane-major ordering == reference argmax
  unsigned long long bm = __ballot(mx0 == mx);
  int wl = (int)__builtin_ctzll(bm);
  int mwin = __builtin_amdgcn_readlane(mi, wl);
  int sk = wl * 8 + mwin;  // wave-uniform
  idx[K] = sk;

  const float* grow_base = G + (size_t)sk * KDIM;
  if constexpr (K < 3) {
    const float4* gp = (const float4*)(grow_base + lane * 8);
    float4 r0 = gp[0], r1 = gp[1];
    Grow[K][0] = r0.x; Grow[K][1] = r0.y; Grow[K][2] = r0.z; Grow[K][3] = r0.w;
    Grow[K][4] = r1.x; Grow[K][5] = r1.y; Grow[K][6] = r1.z; Grow[K][7] = r1.w;
  }

#pragma unroll
  for (int b2 = 0; b2 < K; ++b2) {
    float v = grow_base[idx[b2]];
    gs[K][b2] = v;
    gs[b2][K] = v;
  }
  gs[K][K] = grow_base[sk];
  // rhs from registers: alpha0[sk] lives in lane sk>>3, slot sk&7
  float pick = a0[0];
#pragma unroll
  for (int j = 1; j < 8; ++j) pick = (mwin == j) ? a0[j] : pick;
  rhs[K] = __int_as_float(__builtin_amdgcn_readlane(__float_as_int(pick), wl));

  solve_sz<K + 1>(gs, rhs, gamma);

  if constexpr (K < 3) {
#pragma unroll
    for (int m = 0; m < 8; ++m) {
      float acc2 = a0[m];
#pragma unroll
      for (int a = 0; a <= K; ++a) acc2 = fmaf(-gamma[a], Grow[a][m], acc2);
      al[m] = acc2;
    }
  }
}

// ---- fused alpha0 + OMP: 2048 blocks x 4 waves; 4 signals per wave.
// alpha0 = X @ Dn computed with v_pk_fma into the exact per-lane layout OMP
// consumes (lane l = atoms l*8..+8) -> A0 never touches global memory.
__global__ __launch_bounds__(256) void k_fused(const float* __restrict__ X,
                                               const float* __restrict__ Dil,
                                               const float* __restrict__ G,
                                               float4* __restrict__ wg,
                                               int4* __restrict__ wi) {
  __shared__ __align__(16) float DS[16 * 512];  // one c-chunk of Dil (32 KB)
  __shared__ __align__(16) float Xs[64 * 16];   // X tile: 64 c x 16 w
  int tid = threadIdx.x;
  int lane = tid & 63;
  int wv = __builtin_amdgcn_readfirstlane(tid >> 6);
  int bid = (int)blockIdx.x;
  int mt = bid >> 2, w0 = (bid & 3) * 16;  // mt = b*64+h
  int b = mt >> 6, h = mt & 63;

#pragma unroll
  for (int i = 0; i < 4; ++i) {
    int flat = i * 256 + tid;
    int c = flat >> 4, wz = flat & 15;
    Xs[c * 16 + wz] = X[(((size_t)b * CDIM + c) * HQ + h) * WQ + w0 + wz];
  }

  v2f acc[4][4] = {};  // [signal][atom-pair]
  const float4* Dil4 = (const float4*)Dil;
  float4* DS4 = (float4*)DS;
  for (int nc = 0; nc < 4; ++nc) {
    float4 r[8];
#pragma unroll
    for (int i = 0; i < 8; ++i) r[i] = Dil4[nc * 2048 + i * 256 + tid];
    __syncthreads();  // prev chunk's compute done (also covers Xs at nc=0)
#pragma unroll
    for (int i = 0; i < 8; ++i) DS4[i * 256 + tid] = r[i];
    __syncthreads();
#pragma unroll
    for (int cc = 0; cc < 16; ++cc) {
      float4 xv = *(const float4*)&Xs[(nc * 16 + cc) * 16 + wv * 4];  // broadcast
      float4 dA = *(const float4*)&DS[(cc * 2 + 0) * 256 + lane * 4];  // contig b128
      float4 dB = *(const float4*)&DS[(cc * 2 + 1) * 256 + lane * 4];  // contig b128
      v2f d0 = {dA.x, dA.y}, d1 = {dA.z, dA.w}, d2 = {dB.x, dB.y}, d3 = {dB.z, dB.w};
      v2f x0 = {xv.x, xv.x}, x1 = {xv.y, xv.y}, x2 = {xv.z, xv.z}, x3 = {xv.w, xv.w};
      acc[0][0] = __builtin_elementwise_fma(x0, d0, acc[0][0]);
      acc[0][1] = __builtin_elementwise_fma(x0, d1, acc[0][1]);
      acc[0][2] = __builtin_elementwise_fma(x0, d2, acc[0][2]);
      acc[0][3] = __builtin_elementwise_fma(x0, d3, acc[0][3]);
      acc[1][0] = __builtin_elementwise_fma(x1, d0, acc[1][0]);
      acc[1][1] = __builtin_elementwise_fma(x1, d1, acc[1][1]);
      acc[1][2] = __builtin_elementwise_fma(x1, d2, acc[1][2]);
      acc[1][3] = __builtin_elementwise_fma(x1, d3, acc[1][3]);
      acc[2][0] = __builtin_elementwise_fma(x2, d0, acc[2][0]);
      acc[2][1] = __builtin_elementwise_fma(x2, d1, acc[2][1]);
      acc[2][2] = __builtin_elementwise_fma(x2, d2, acc[2][2]);
      acc[2][3] = __builtin_elementwise_fma(x2, d3, acc[2][3]);
      acc[3][0] = __builtin_elementwise_fma(x3, d0, acc[3][0]);
      acc[3][1] = __builtin_elementwise_fma(x3, d1, acc[3][1]);
      acc[3][2] = __builtin_elementwise_fma(x3, d2, acc[3][2]);
      acc[3][3] = __builtin_elementwise_fma(x3, d3, acc[3][3]);
    }
  }

  // ---- OMP: 4 signals sequentially (runtime loop keeps I-cache small;
  // a0 extraction branches are static-indexed, no scratch).
  int nb = mt * 64 + w0 + wv * 4;
#pragma unroll 1
  for (int s = 0; s < 4; ++s) {
    float a0[8];
    if (s == 0) {
      a0[0] = acc[0][0].x; a0[1] = acc[0][0].y; a0[2] = acc[0][1].x; a0[3] = acc[0][1].y;
      a0[4] = acc[0][2].x; a0[5] = acc[0][2].y; a0[6] = acc[0][3].x; a0[7] = acc[0][3].y;
    } else if (s == 1) {
      a0[0] = acc[1][0].x; a0[1] = acc[1][0].y; a0[2] = acc[1][1].x; a0[3] = acc[1][1].y;
      a0[4] = acc[1][2].x; a0[5] = acc[1][2].y; a0[6] = acc[1][3].x; a0[7] = acc[1][3].y;
    } else if (s == 2) {
      a0[0] = acc[2][0].x; a0[1] = acc[2][0].y; a0[2] = acc[2][1].x; a0[3] = acc[2][1].y;
      a0[4] = acc[2][2].x; a0[5] = acc[2][2].y; a0[6] = acc[2][3].x; a0[7] = acc[2][3].y;
    } else {
      a0[0] = acc[3][0].x; a0[1] = acc[3][0].y; a0[2] = acc[3][1].x; a0[3] = acc[3][1].y;
      a0[4] = acc[3][2].x; a0[5] = acc[3][2].y; a0[6] = acc[3][3].x; a0[7] = acc[3][3].y;
    }
    float al[8];
#pragma unroll
    for (int m = 0; m < 8; ++m) al[m] = a0[m];
    float Grow[3][8];
    float gs[4][4];
    float rhs[4];
    int idx[4];
    float gamma[4];
    omp_step2<0>(lane, G, a0, al, Grow, gs, rhs, idx, gamma);
    omp_step2<1>(lane, G, a0, al, Grow, gs, rhs, idx, gamma);
    omp_step2<2>(lane, G, a0, al, Grow, gs, rhs, idx, gamma);
    omp_step2<3>(lane, G, a0, al, Grow, gs, rhs, idx, gamma);
    // dedupe: scatter-set semantics — later slot with same index wins
    bool k0 = (idx[0] != idx[1]) && (idx[0] != idx[2]) && (idx[0] != idx[3]);
    bool k1 = (idx[1] != idx[2]) && (idx[1] != idx[3]);
    bool k2 = (idx[2] != idx[3]);
    if (lane == 0) {
      wg[nb + s] = make_float4(k0 ? gamma[0] : 0.f, k1 ? gamma[1] : 0.f,
                               k2 ? gamma[2] : 0.f, gamma[3]);
      wi[nb + s] = make_int4(idx[0], idx[1], idx[2], idx[3]);
    }
  }
}

// ---- fused epilogue: blocks 0..511 quant+stats, 512..2559 dense ids ----
__global__ __launch_bounds__(256) void k_ei(const float* __restrict__ X,
                                            const float* __restrict__ DnT,
                                            const float4* __restrict__ wg,
                                            const int4* __restrict__ wi,
                                            float* __restrict__ out,
                                            double* __restrict__ accs,
                                            int* __restrict__ hist) {
  __shared__ __align__(16) int sIdx[64][4];
  __shared__ __align__(16) float sKg[64][4];
  __shared__ float q[64 * 65];
  __shared__ float red[4];
  int tid = threadIdx.x;

  if (blockIdx.x < 512) {
    int bh = blockIdx.x;
    int b = bh >> 6, h = bh & 63;
    if (tid < 64) {
      int w = tid;
      int n = bh * 64 + w;
      int4 iv = wi[n];
      float4 gv = wg[n];  // already deduped in k_fused
      sIdx[w][0] = iv.x; sIdx[w][1] = iv.y; sIdx[w][2] = iv.z; sIdx[w][3] = iv.w;
      sKg[w][0] = gv.x; sKg[w][1] = gv.y; sKg[w][2] = gv.z; sKg[w][3] = gv.w;
      int nz = (int)(gv.x != 0.f) + (int)(gv.y != 0.f) +
               (int)(gv.z != 0.f) + (int)(gv.w != 0.f);
      float s = fabsf(gv.x) + fabsf(gv.y) + fabsf(gv.z) + fabsf(gv.w);
#pragma unroll
      for (int off = 32; off >= 1; off >>= 1) s += __shfl_xor(s, off);
#pragma unroll
      for (int v = 0; v < 5; ++v) {
        unsigned long long m = __ballot(nz == v);
        if (tid == 0) {
          int c = (int)__popcll(m);
          if (c) atomicAdd(&hist[v], c);
        }
      }
      if (tid == 0) atomicAdd(&accs[0], (double)s);
    }
    __syncthreads();

    int w2 = tid & 63, p = tid >> 6, c0 = p * 16;
    float acc[16] = {};
#pragma unroll
    for (int s = 0; s < 4; ++s) {
      int ks = sIdx[w2][s];
      float g = sKg[w2][s];
      const float4* dp = (const float4*)(DnT + (size_t)ks * CDIM + c0);
#pragma unroll
      for (int i4 = 0; i4 < 4; ++i4) {
        float4 d = dp[i4];
        acc[i4 * 4 + 0] = fmaf(g, d.x, acc[i4 * 4 + 0]);
        acc[i4 * 4 + 1] = fmaf(g, d.y, acc[i4 * 4 + 1]);
        acc[i4 * 4 + 2] = fmaf(g, d.z, acc[i4 * 4 + 2]);
        acc[i4 * 4 + 3] = fmaf(g, d.w, acc[i4 * 4 + 3]);
      }
    }
#pragma unroll
    for (int i = 0; i < 16; ++i) q[(c0 + i) * 65 + w2] = acc[i];
    __syncthreads();

    float sumsq = 0.f;
#pragma unroll
    for (int pass = 0; pass < 16; ++pass) {
      int c = pass * 4 + p;
      float qv = q[c * 65 + w2];
      size_t off = (((size_t)b * CDIM + c) * HQ + h) * WQ + w2;
      float xv = X[off];
      float d = qv - xv;
      sumsq = fmaf(d, d, sumsq);
      out[off] = qv;
    }

#pragma unroll
    for (int off = 32; off >= 1; off >>= 1) sumsq += __shfl_xor(sumsq, off);
    if ((tid & 63) == 0) red[tid >> 6] = sumsq;
    __syncthreads();
    if (tid == 0) atomicAdd(&accs[1], (double)(red[0] + red[1] + red[2] + red[3]));
  } else {
    // ---------------- dense ids write (dwordx4, 4 signals/thread) ----------------
    int bid = blockIdx.x - 512;
    int bh = bid >> 2, kq = bid & 3;
    int b = bh >> 6, h = bh & 63;
    if (tid < 64) {
      int n = bh * 64 + tid;
      *(int4*)&sIdx[tid][0] = wi[n];
      *(float4*)&sKg[tid][0] = wg[n];
    }
    __syncthreads();
    int w4 = (tid & 15) * 4, kl = tid >> 4;
    int4 I0 = *(const int4*)&sIdx[w4][0];
    int4 I1 = *(const int4*)&sIdx[w4 + 1][0];
    int4 I2 = *(const int4*)&sIdx[w4 + 2][0];
    int4 I3 = *(const int4*)&sIdx[w4 + 3][0];
    float4 G0 = *(const float4*)&sKg[w4][0];
    float4 G1 = *(const float4*)&sKg[w4 + 1][0];
    float4 G2 = *(const float4*)&sKg[w4 + 2][0];
    float4 G3 = *(const float4*)&sKg[w4 + 3][0];
    float* ids = out + IDS_OFF;
    size_t base = (((size_t)b * KDIM + kq * 128 + kl) * HQ + h) * WQ + w4;
#pragma unroll
    for (int pass = 0; pass < 8; ++pass) {
      int k = kq * 128 + pass * 16 + kl;
      // reverse-order select chain = scatter last-wins semantics
      float4 v;
      v.x = (k == I0.w) ? G0.w : (k == I0.z) ? G0.z : (k == I0.y) ? G0.y : (k == I0.x) ? G0.x : 0.f;
      v.y = (k == I1.w) ? G1.w : (k == I1.z) ? G1.z : (k == I1.y) ? G1.y : (k == I1.x) ? G1.x : 0.f;
      v.z = (k == I2.w) ? G2.w : (k == I2.z) ? G2.z : (k == I2.y) ? G2.y : (k == I2.x) ? G2.x : 0.f;
      v.w = (k == I3.w) ? G3.w : (k == I3.z) ? G3.z : (k == I3.y) ? G3.y : (k == I3.x) ? G3.x : 0.f;
      *(float4*)&ids[base + (size_t)pass * 16 * 4096] = v;
    }
  }
}

// ---- finalize scalars (separate 1-block dispatch; stream order = no fence needed) ----
__global__ __launch_bounds__(64) void k_final(const double* __restrict__ accs,
                                              const int* __restrict__ hist,
                                              const float* __restrict__ pd,
                                              float* __restrict__ out) {
  if (threadIdx.x == 0) {
    float sumAbsD = 0.f;
#pragma unroll
    for (int i = 0; i < 8; ++i) sumAbsD += pd[i];
    double sumAbsZ = accs[0], sumSq = accs[1];
    float diff = (float)(sumSq / 2097152.0);
    out[DIFF_ENC_OFF] = diff;
    out[DIFF_DICT_OFF] = diff;
    out[NUM_STEPS_OFF] = 4.0f;
    out[MEAN_D_OFF] = sumAbsD / 32768.0f;
    out[MEAN_Z_OFF] = (float)(sumAbsZ / 16777216.0);
    int h0 = hist[0], h1 = hist[1], h2 = hist[2], h3 = hist[3], h4 = hist[4];
    out[NORM_Z_OFF] = (float)((double)(h1 + 2 * h2 + 3 * h3 + 4 * h4) / 32768.0);
    int cum = 0, res = 0;
    for (int v = 4; v >= 0; --v) {
      cum += hist[v];
      if (cum >= 327) { res = v; break; }
    }
    out[TOP_PCT_OFF] = (float)res;
    out[NUM_ZEROS_OFF] = (float)h0;
  }
}

extern "C" void kernel_launch(void* const* d_in, const int* in_sizes, int n_in,
                              void* d_out, int out_size, void* d_ws, size_t ws_size,
                              hipStream_t stream) {
  (void)in_sizes; (void)n_in; (void)out_size; (void)ws_size;
  const float* X = (const float*)d_in[0];    // [8,64,64,64]
  const float* D = (const float*)d_in[1];    // [64,512]
  float* out = (float*)d_out;
  float* W = (float*)d_ws;
  double* accs = (double*)d_ws;
  int* hist = (int*)W + 4;
  float* pd = W + WS_PD;
  float* DnT = W + WS_DNT;
  float* G = W + WS_G;
  float4* wgam = (float4*)(W + WS_WG);
  int4* widx = (int4*)(W + WS_WI);
  float* Dil = out + DIL_OFF;  // staged in ids region; k_ei overwrites later

  hipLaunchKernelGGL(k_g, dim3(64), dim3(256), 0, stream, D, G, DnT, pd, Dil, W);
  hipLaunchKernelGGL(k_fused, dim3(2048), dim3(256), 0, stream, X, Dil, G, wgam, widx);
  hipLaunchKernelGGL(k_ei, dim3(2560), dim3(256), 0, stream, X, DnT, wgam, widx, out, accs, hist);
  hipLaunchKernelGGL(k_final, dim3(1), dim3(64), 0, stream, accs, hist, pd, out);
}

// Round 2
// 189.362 us; speedup vs baseline: 1.2466x; 1.2466x over previous
//
#include <hip/hip_runtime.h>
#include <cstdint>
#include <cstddef>

// Problem constants
#define BQ 8
#define CDIM 64
#define HQ 64
#define WQ 64
#define KDIM 512
#define N_SIG 32768   // B*H*W
#define S_NNZ 4

// d_out float offsets (outputs concatenated flat in return order)
#define DIFF_ENC_OFF 2097152
#define DIFF_DICT_OFF 2097153
#define IDS_OFF 2097154
#define NUM_STEPS_OFF 18874370
#define MEAN_D_OFF 18874371
#define MEAN_Z_OFF 18874372
#define NORM_Z_OFF 18874373
#define TOP_PCT_OFF 18874374
#define NUM_ZEROS_OFF 18874375

// ws float-offsets
// words [0..3]  : accs[2] doubles: sumAbsZ, sumSq (zeroed by k_g block 0)
// words [4..8]  : hist[5] ints                    (zeroed by k_g block 0)
// [16..24)      : pd[8] per-diagonal-block |Dn| partial sums
#define WS_PD 16
#define WS_DNT 24
#define WS_G 32792
#define WS_WG 294936   // float4 per signal (deduped gamma)
#define WS_WI 426008   // int4 per signal (idx)

// Interleaved normalized dictionary staged in d_out's ids region (written by
// k_g, consumed by k_fused, overwritten later by k_ei). Layout:
//   Dil[((c*2 + j)*64 + l)*4 + f] = Dn[c][l*8 + j*4 + f]
// so lane l reads its 8 atoms for row c as two contiguous float4 loads.
#define DIL_OFF 4194304

typedef float v2f __attribute__((ext_vector_type(2)));

// ---- Gram kernel: 64 blocks, G = Dn^T Dn (8x8 tiles of 64); diagonal blocks
// also emit DnT, Dil and pd. alpha0 is never materialized in global memory.
__global__ __launch_bounds__(256) void k_g(const float* __restrict__ D,
                                           float* __restrict__ G,
                                           float* __restrict__ DnT,
                                           float* __restrict__ pd,
                                           float* __restrict__ Dil,
                                           float* __restrict__ W) {
  __shared__ float Xs[64 * 64];
  __shared__ float Dns[64 * 64];
  __shared__ float partA[4][64];
  __shared__ float partB[4][64];
  __shared__ float invA[64];
  __shared__ float invB[64];
  int tid = threadIdx.x;
  int w = tid & 63, cq = tid >> 6;
  int ty = tid >> 4, tx = tid & 15;
  if (blockIdx.x == 0 && tid < 16) ((unsigned int*)W)[tid] = 0u;  // accs+hist zero

  int ti = (int)blockIdx.x >> 3, tj = (int)blockIdx.x & 7;
#pragma unroll
  for (int p = 0; p < 16; ++p) {
    int c = p * 4 + cq;
    Xs[c * 64 + w] = D[(size_t)c * KDIM + ti * 64 + w];
    Dns[c * 64 + w] = D[(size_t)c * KDIM + tj * 64 + w];
  }
  __syncthreads();
  float ssA = 0.f, ssB = 0.f;
#pragma unroll
  for (int cc = 0; cc < 16; ++cc) {
    int c = cq * 16 + cc;
    float a = Xs[c * 64 + w];
    ssA = fmaf(a, a, ssA);
    float bv = Dns[c * 64 + w];
    ssB = fmaf(bv, bv, ssB);
  }
  partA[cq][w] = ssA;
  partB[cq][w] = ssB;
  __syncthreads();
  if (tid < 64) {
    invA[tid] = 1.0f / sqrtf(partA[0][tid] + partA[1][tid] + partA[2][tid] + partA[3][tid]);
    invB[tid] = 1.0f / sqrtf(partB[0][tid] + partB[1][tid] + partB[2][tid] + partB[3][tid]);
  }
  __syncthreads();
  if (ti == tj) {
    // emit normalized DnT rows, interleaved Dil slice, pd[ti] = sum|Dn| partial
    int kl = tid >> 2, cp = (tid & 3) * 16;
    float ia = invA[kl];
    int kg = ti * 64 + kl;              // global atom index
    int il = kg >> 3, ij = (kg >> 2) & 1, iff = kg & 3;
    float sabs = 0.f;
#pragma unroll
    for (int i = 0; i < 16; ++i) {
      int c = cp + i;
      float v = Xs[c * 64 + kl] * ia;
      DnT[(size_t)kg * CDIM + c] = v;
      Dil[((c * 2 + ij) * 64 + il) * 4 + iff] = v;
      sabs += fabsf(v);
    }
#pragma unroll
    for (int off = 32; off >= 1; off >>= 1) sabs += __shfl_xor(sabs, off);
    __syncthreads();
    if ((tid & 63) == 0) partA[0][tid >> 6] = sabs;
    __syncthreads();
    if (tid == 0) pd[ti] = partA[0][0] + partA[0][1] + partA[0][2] + partA[0][3];
  }
  v2f acc[4][2] = {};
  for (int c = 0; c < 64; ++c) {
    float4 avv = *(const float4*)&Xs[c * 64 + ty * 4];
    float av[4] = {avv.x, avv.y, avv.z, avv.w};
    float4 bv = *(const float4*)&Dns[c * 64 + tx * 4];
    v2f b0 = {bv.x, bv.y}, b1 = {bv.z, bv.w};
#pragma unroll
    for (int i = 0; i < 4; ++i) {
      v2f a2 = {av[i], av[i]};
      acc[i][0] = __builtin_elementwise_fma(a2, b0, acc[i][0]);
      acc[i][1] = __builtin_elementwise_fma(a2, b1, acc[i][1]);
    }
  }
  float sn[4] = {invB[tx * 4], invB[tx * 4 + 1], invB[tx * 4 + 2], invB[tx * 4 + 3]};
#pragma unroll
  for (int i = 0; i < 4; ++i) {
    float im = invA[ty * 4 + i];
    float4 st = make_float4(acc[i][0].x * im * sn[0], acc[i][0].y * im * sn[1],
                            acc[i][1].x * im * sn[2], acc[i][1].y * im * sn[3]);
    *(float4*)&G[(size_t)(ti * 64 + ty * 4 + i) * KDIM + tj * 64 + tx * 4] = st;
  }
}

// ---- DPP wave-64 max of a non-negative float; returns wave-uniform (SGPR) value ----
__device__ __forceinline__ float wave_absmax_u(float m) {
#define DPP_MAX(ctrl)                                                              \
  {                                                                                \
    int t_ = __builtin_amdgcn_update_dpp(0, __float_as_int(m), (ctrl), 0xf, 0xf,   \
                                         true);                                    \
    m = fmaxf(m, __int_as_float(t_));                                              \
  }
  DPP_MAX(0x111) DPP_MAX(0x112) DPP_MAX(0x114) DPP_MAX(0x118)
  DPP_MAX(0x142) DPP_MAX(0x143)
#undef DPP_MAX
  return __int_as_float(__builtin_amdgcn_readlane(__float_as_int(m), 63));
}

// ---- fp32 solve, no pivoting (G_II near-identity), saved reciprocals ----
template <int SZ>
__device__ __forceinline__ void solve_sz(const float (&gs)[4][4], const float (&rhs)[4],
                                         float (&gamma)[4]) {
  float M[SZ][SZ];
  float y[SZ];
  float idg[SZ];
#pragma unroll
  for (int a = 0; a < SZ; ++a) {
    y[a] = rhs[a];
#pragma unroll
    for (int b = 0; b < SZ; ++b) M[a][b] = gs[a][b] + (a == b ? 1e-7f : 0.0f);
  }
#pragma unroll
  for (int p = 0; p < SZ; ++p) {
    float ip = __builtin_amdgcn_rcpf(M[p][p]);
    idg[p] = ip;
#pragma unroll
    for (int r = p + 1; r < SZ; ++r) {
      float f = M[r][p] * ip;
#pragma unroll
      for (int c = p + 1; c < SZ; ++c) M[r][c] = fmaf(-f, M[p][c], M[r][c]);
      y[r] = fmaf(-f, y[p], y[r]);
    }
  }
#pragma unroll
  for (int r = SZ - 1; r >= 0; --r) {
    float t = y[r];
#pragma unroll
    for (int c = r + 1; c < SZ; ++c) t = fmaf(-M[r][c], gamma[c], t);
    gamma[r] = t * idg[r];
  }
}

// ---- one OMP step, alpha fully in registers (lane l owns atoms l*8..l*8+8) ----
template <int K>
__device__ __forceinline__ void omp_step2(int lane, const float* __restrict__ G,
                                          const float (&a0)[8], float (&al)[8],
                                          float (&Grow)[3][8], float (&gs)[4][4],
                                          float (&rhs)[4], int (&idx)[4],
                                          float (&gamma)[4]) {
  // per-lane argmax with lowest-m tie-break (strict >)
  float mx0 = fabsf(al[0]);
  int mi = 0;
#pragma unroll
  for (int m = 1; m < 8; ++m) {
    float v = fabsf(al[m]);
    mi = (v > mx0) ? m : mi;
    mx0 = fmaxf(v, mx0);
  }
  float mx = wave_absmax_u(mx0);  // wave-uniform SGPR
  // single ballot; lowest lane wins; lane-major ordering == reference argmax
  unsigned long long bm = __ballot(mx0 == mx);
  int wl = (int)__builtin_ctzll(bm);
  int mwin = __builtin_amdgcn_readlane(mi, wl);
  int sk = wl * 8 + mwin;  // wave-uniform
  idx[K] = sk;

  const float* grow_base = G + (size_t)sk * KDIM;
  if constexpr (K < 3) {
    const float4* gp = (const float4*)(grow_base + lane * 8);
    float4 r0 = gp[0], r1 = gp[1];
    Grow[K][0] = r0.x; Grow[K][1] = r0.y; Grow[K][2] = r0.z; Grow[K][3] = r0.w;
    Grow[K][4] = r1.x; Grow[K][5] = r1.y; Grow[K][6] = r1.z; Grow[K][7] = r1.w;
  }

#pragma unroll
  for (int b2 = 0; b2 < K; ++b2) {
    float v = grow_base[idx[b2]];
    gs[K][b2] = v;
    gs[b2][K] = v;
  }
  gs[K][K] = grow_base[sk];
  // rhs from registers: alpha0[sk] lives in lane sk>>3, slot sk&7
  float pick = a0[0];
#pragma unroll
  for (int j = 1; j < 8; ++j) pick = (mwin == j) ? a0[j] : pick;
  rhs[K] = __int_as_float(__builtin_amdgcn_readlane(__float_as_int(pick), wl));

  solve_sz<K + 1>(gs, rhs, gamma);

  if constexpr (K < 3) {
#pragma unroll
    for (int m = 0; m < 8; ++m) {
      float acc2 = a0[m];
#pragma unroll
      for (int a = 0; a <= K; ++a) acc2 = fmaf(-gamma[a], Grow[a][m], acc2);
      al[m] = acc2;
    }
  }
}

// ---- fused alpha0 + OMP: 1024 blocks x 4 waves; 8 signals per wave.
// GEMM phase: alpha accumulated in registers (v_pk_fma), Dn streamed straight
// from L2 (128 KB, resident). Alpha then parked in LDS (wave-private, plane-
// major contiguous float4 -> conflict-free), so the accumulator tile is DEAD
// before the OMP phase begins: no register spill (round-1 failure mode).
__global__ __launch_bounds__(256, 2) void k_fused(const float* __restrict__ X,
                                                  const float* __restrict__ Dil,
                                                  const float* __restrict__ G,
                                                  float4* __restrict__ wg,
                                                  int4* __restrict__ wi) {
  __shared__ __align__(16) float AS[32 * 512];  // alpha park: 32 signals (64 KB)
  __shared__ __align__(16) float Xs[64 * 32];   // X tile: 64 c x 32 w (8 KB)
  int tid = threadIdx.x;
  int lane = tid & 63;
  int wv = __builtin_amdgcn_readfirstlane(tid >> 6);
  int bid = (int)blockIdx.x;
  int mt = bid >> 1, w0 = (bid & 1) * 32;  // mt = b*64+h
  int b = mt >> 6, h = mt & 63;

  // stage X tile: 512 float4, 2 per thread; 128B-contiguous per channel
#pragma unroll
  for (int i = 0; i < 2; ++i) {
    int fi = i * 256 + tid;
    int c = fi >> 3, w4 = (fi & 7) * 4;
    *(float4*)&Xs[c * 32 + w4] =
        *(const float4*)&X[(((size_t)b * CDIM + c) * HQ + h) * WQ + w0 + w4];
  }
  __syncthreads();

  // ---- GEMM: acc[signal][atom-pair], 64 VGPRs, dies at the LDS park ----
  v2f acc[8][4] = {};
  const float4* Dil4 = (const float4*)Dil;
#pragma unroll 2
  for (int c = 0; c < 64; ++c) {
    float4 g0 = Dil4[c * 128 + lane];        // atoms lane*8+0..3, L2-resident
    float4 g1 = Dil4[c * 128 + 64 + lane];   // atoms lane*8+4..7
    float4 xa = *(const float4*)&Xs[c * 32 + wv * 8];      // signals 0..3 (bcast)
    float4 xb = *(const float4*)&Xs[c * 32 + wv * 8 + 4];  // signals 4..7 (bcast)
    v2f d0 = {g0.x, g0.y}, d1 = {g0.z, g0.w}, d2 = {g1.x, g1.y}, d3 = {g1.z, g1.w};
    float xv[8] = {xa.x, xa.y, xa.z, xa.w, xb.x, xb.y, xb.z, xb.w};
#pragma unroll
    for (int s = 0; s < 8; ++s) {
      v2f xx = {xv[s], xv[s]};
      acc[s][0] = __builtin_elementwise_fma(xx, d0, acc[s][0]);
      acc[s][1] = __builtin_elementwise_fma(xx, d1, acc[s][1]);
      acc[s][2] = __builtin_elementwise_fma(xx, d2, acc[s][2]);
      acc[s][3] = __builtin_elementwise_fma(xx, d3, acc[s][3]);
    }
  }

  // ---- park alpha in LDS (wave-private region; no barrier needed) ----
  float4* AS4 = (float4*)AS;
#pragma unroll
  for (int s = 0; s < 8; ++s) {
    int sig = wv * 8 + s;
    AS4[sig * 128 + lane] =
        make_float4(acc[s][0].x, acc[s][0].y, acc[s][1].x, acc[s][1].y);
    AS4[sig * 128 + 64 + lane] =
        make_float4(acc[s][2].x, acc[s][2].y, acc[s][3].x, acc[s][3].y);
  }

  // ---- OMP: 8 signals sequentially; a0 reloaded per signal from LDS ----
  int nb = mt * 64 + w0 + wv * 8;
#pragma unroll 1
  for (int s = 0; s < 8; ++s) {
    int sig = wv * 8 + s;
    float4 p0 = AS4[sig * 128 + lane];
    float4 p1 = AS4[sig * 128 + 64 + lane];
    float a0[8] = {p0.x, p0.y, p0.z, p0.w, p1.x, p1.y, p1.z, p1.w};
    float al[8];
#pragma unroll
    for (int m = 0; m < 8; ++m) al[m] = a0[m];
    float Grow[3][8];
    float gs[4][4];
    float rhs[4];
    int idx[4];
    float gamma[4];
    omp_step2<0>(lane, G, a0, al, Grow, gs, rhs, idx, gamma);
    omp_step2<1>(lane, G, a0, al, Grow, gs, rhs, idx, gamma);
    omp_step2<2>(lane, G, a0, al, Grow, gs, rhs, idx, gamma);
    omp_step2<3>(lane, G, a0, al, Grow, gs, rhs, idx, gamma);
    // dedupe: scatter-set semantics — later slot with same index wins
    bool k0 = (idx[0] != idx[1]) && (idx[0] != idx[2]) && (idx[0] != idx[3]);
    bool k1 = (idx[1] != idx[2]) && (idx[1] != idx[3]);
    bool k2 = (idx[2] != idx[3]);
    if (lane == 0) {
      wg[nb + s] = make_float4(k0 ? gamma[0] : 0.f, k1 ? gamma[1] : 0.f,
                               k2 ? gamma[2] : 0.f, gamma[3]);
      wi[nb + s] = make_int4(idx[0], idx[1], idx[2], idx[3]);
    }
  }
}

// ---- fused epilogue: blocks 0..511 quant+stats, 512..2559 dense ids ----
__global__ __launch_bounds__(256) void k_ei(const float* __restrict__ X,
                                            const float* __restrict__ DnT,
                                            const float4* __restrict__ wg,
                                            const int4* __restrict__ wi,
                                            float* __restrict__ out,
                                            double* __restrict__ accs,
                                            int* __restrict__ hist) {
  __shared__ __align__(16) int sIdx[64][4];
  __shared__ __align__(16) float sKg[64][4];
  __shared__ float q[64 * 65];
  __shared__ float red[4];
  int tid = threadIdx.x;

  if (blockIdx.x < 512) {
    int bh = blockIdx.x;
    int b = bh >> 6, h = bh & 63;
    if (tid < 64) {
      int w = tid;
      int n = bh * 64 + w;
      int4 iv = wi[n];
      float4 gv = wg[n];  // already deduped in k_fused
      sIdx[w][0] = iv.x; sIdx[w][1] = iv.y; sIdx[w][2] = iv.z; sIdx[w][3] = iv.w;
      sKg[w][0] = gv.x; sKg[w][1] = gv.y; sKg[w][2] = gv.z; sKg[w][3] = gv.w;
      int nz = (int)(gv.x != 0.f) + (int)(gv.y != 0.f) +
               (int)(gv.z != 0.f) + (int)(gv.w != 0.f);
      float s = fabsf(gv.x) + fabsf(gv.y) + fabsf(gv.z) + fabsf(gv.w);
#pragma unroll
      for (int off = 32; off >= 1; off >>= 1) s += __shfl_xor(s, off);
#pragma unroll
      for (int v = 0; v < 5; ++v) {
        unsigned long long m = __ballot(nz == v);
        if (tid == 0) {
          int c = (int)__popcll(m);
          if (c) atomicAdd(&hist[v], c);
        }
      }
      if (tid == 0) atomicAdd(&accs[0], (double)s);
    }
    __syncthreads();

    int w2 = tid & 63, p = tid >> 6, c0 = p * 16;
    float acc[16] = {};
#pragma unroll
    for (int s = 0; s < 4; ++s) {
      int ks = sIdx[w2][s];
      float g = sKg[w2][s];
      const float4* dp = (const float4*)(DnT + (size_t)ks * CDIM + c0);
#pragma unroll
      for (int i4 = 0; i4 < 4; ++i4) {
        float4 d = dp[i4];
        acc[i4 * 4 + 0] = fmaf(g, d.x, acc[i4 * 4 + 0]);
        acc[i4 * 4 + 1] = fmaf(g, d.y, acc[i4 * 4 + 1]);
        acc[i4 * 4 + 2] = fmaf(g, d.z, acc[i4 * 4 + 2]);
        acc[i4 * 4 + 3] = fmaf(g, d.w, acc[i4 * 4 + 3]);
      }
    }
#pragma unroll
    for (int i = 0; i < 16; ++i) q[(c0 + i) * 65 + w2] = acc[i];
    __syncthreads();

    float sumsq = 0.f;
#pragma unroll
    for (int pass = 0; pass < 16; ++pass) {
      int c = pass * 4 + p;
      float qv = q[c * 65 + w2];
      size_t off = (((size_t)b * CDIM + c) * HQ + h) * WQ + w2;
      float xv = X[off];
      float d = qv - xv;
      sumsq = fmaf(d, d, sumsq);
      out[off] = qv;
    }

#pragma unroll
    for (int off = 32; off >= 1; off >>= 1) sumsq += __shfl_xor(sumsq, off);
    if ((tid & 63) == 0) red[tid >> 6] = sumsq;
    __syncthreads();
    if (tid == 0) atomicAdd(&accs[1], (double)(red[0] + red[1] + red[2] + red[3]));
  } else {
    // ---------------- dense ids write (dwordx4, 4 signals/thread) ----------------
    int bid = blockIdx.x - 512;
    int bh = bid >> 2, kq = bid & 3;
    int b = bh >> 6, h = bh & 63;
    if (tid < 64) {
      int n = bh * 64 + tid;
      *(int4*)&sIdx[tid][0] = wi[n];
      *(float4*)&sKg[tid][0] = wg[n];
    }
    __syncthreads();
    int w4 = (tid & 15) * 4, kl = tid >> 4;
    int4 I0 = *(const int4*)&sIdx[w4][0];
    int4 I1 = *(const int4*)&sIdx[w4 + 1][0];
    int4 I2 = *(const int4*)&sIdx[w4 + 2][0];
    int4 I3 = *(const int4*)&sIdx[w4 + 3][0];
    float4 G0 = *(const float4*)&sKg[w4][0];
    float4 G1 = *(const float4*)&sKg[w4 + 1][0];
    float4 G2 = *(const float4*)&sKg[w4 + 2][0];
    float4 G3 = *(const float4*)&sKg[w4 + 3][0];
    float* ids = out + IDS_OFF;
    size_t base = (((size_t)b * KDIM + kq * 128 + kl) * HQ + h) * WQ + w4;
#pragma unroll
    for (int pass = 0; pass < 8; ++pass) {
      int k = kq * 128 + pass * 16 + kl;
      // reverse-order select chain = scatter last-wins semantics
      float4 v;
      v.x = (k == I0.w) ? G0.w : (k == I0.z) ? G0.z : (k == I0.y) ? G0.y : (k == I0.x) ? G0.x : 0.f;
      v.y = (k == I1.w) ? G1.w : (k == I1.z) ? G1.z : (k == I1.y) ? G1.y : (k == I1.x) ? G1.x : 0.f;
      v.z = (k == I2.w) ? G2.w : (k == I2.z) ? G2.z : (k == I2.y) ? G2.y : (k == I2.x) ? G2.x : 0.f;
      v.w = (k == I3.w) ? G3.w : (k == I3.z) ? G3.z : (k == I3.y) ? G3.y : (k == I3.x) ? G3.x : 0.f;
      *(float4*)&ids[base + (size_t)pass * 16 * 4096] = v;
    }
  }
}

// ---- finalize scalars (separate 1-block dispatch; stream order = no fence needed) ----
__global__ __launch_bounds__(64) void k_final(const double* __restrict__ accs,
                                              const int* __restrict__ hist,
                                              const float* __restrict__ pd,
                                              float* __restrict__ out) {
  if (threadIdx.x == 0) {
    float sumAbsD = 0.f;
#pragma unroll
    for (int i = 0; i < 8; ++i) sumAbsD += pd[i];
    double sumAbsZ = accs[0], sumSq = accs[1];
    float diff = (float)(sumSq / 2097152.0);
    out[DIFF_ENC_OFF] = diff;
    out[DIFF_DICT_OFF] = diff;
    out[NUM_STEPS_OFF] = 4.0f;
    out[MEAN_D_OFF] = sumAbsD / 32768.0f;
    out[MEAN_Z_OFF] = (float)(sumAbsZ / 16777216.0);
    int h0 = hist[0], h1 = hist[1], h2 = hist[2], h3 = hist[3], h4 = hist[4];
    out[NORM_Z_OFF] = (float)((double)(h1 + 2 * h2 + 3 * h3 + 4 * h4) / 32768.0);
    int cum = 0, res = 0;
    for (int v = 4; v >= 0; --v) {
      cum += hist[v];
      if (cum >= 327) { res = v; break; }
    }
    out[TOP_PCT_OFF] = (float)res;
    out[NUM_ZEROS_OFF] = (float)h0;
  }
}

extern "C" void kernel_launch(void* const* d_in, const int* in_sizes, int n_in,
                              void* d_out, int out_size, void* d_ws, size_t ws_size,
                              hipStream_t stream) {
  (void)in_sizes; (void)n_in; (void)out_size; (void)ws_size;
  const float* X = (const float*)d_in[0];    // [8,64,64,64]
  const float* D = (const float*)d_in[1];    // [64,512]
  float* out = (float*)d_out;
  float* W = (float*)d_ws;
  double* accs = (double*)d_ws;
  int* hist = (int*)W + 4;
  float* pd = W + WS_PD;
  float* DnT = W + WS_DNT;
  float* G = W + WS_G;
  float4* wgam = (float4*)(W + WS_WG);
  int4* widx = (int4*)(W + WS_WI);
  float* Dil = out + DIL_OFF;  // staged in ids region; k_ei overwrites later

  hipLaunchKernelGGL(k_g, dim3(64), dim3(256), 0, stream, D, G, DnT, pd, Dil, W);
  hipLaunchKernelGGL(k_fused, dim3(1024), dim3(256), 0, stream, X, Dil, G, wgam, widx);
  hipLaunchKernelGGL(k_ei, dim3(2560), dim3(256), 0, stream, X, DnT, wgam, widx, out, accs, hist);
  hipLaunchKernelGGL(k_final, dim3(1), dim3(64), 0, stream, accs, hist, pd, out);
}

// Round 3
// 164.554 us; speedup vs baseline: 1.4345x; 1.1508x over previous
//
#include <hip/hip_runtime.h>
#include <cstdint>
#include <cstddef>

// Problem constants
#define BQ 8
#define CDIM 64
#define HQ 64
#define WQ 64
#define KDIM 512
#define N_SIG 32768   // B*H*W
#define S_NNZ 4

// d_out float offsets (outputs concatenated flat in return order)
#define DIFF_ENC_OFF 2097152
#define DIFF_DICT_OFF 2097153
#define IDS_OFF 2097154
#define NUM_STEPS_OFF 18874370
#define MEAN_D_OFF 18874371
#define MEAN_Z_OFF 18874372
#define NORM_Z_OFF 18874373
#define TOP_PCT_OFF 18874374
#define NUM_ZEROS_OFF 18874375

// ws float-offsets
// words [0..3]  : accs[2] doubles: sumAbsZ, sumSq (zeroed by k_g block 0)
// words [4..8]  : hist[5] ints                    (zeroed by k_g block 0)
// [16..24)      : pd[8] per-diagonal-block |Dn| partial sums
#define WS_PD 16
#define WS_DNT 24
#define WS_G 32792
#define WS_WG 294936   // float4 per signal (deduped gamma)
#define WS_WI 426008   // int4 per signal (idx)

// Row-major normalized dictionary Dnr[c*512 + k] staged in d_out's ids region
// (written by k_g, consumed by k_fused, overwritten later by k_ei).
#define DNR_OFF 4194304

typedef float v2f __attribute__((ext_vector_type(2)));

// ---- Gram kernel: 64 blocks, G = Dn^T Dn (8x8 tiles of 64); diagonal blocks
// also emit DnT, Dnr and pd. alpha0 is never materialized in global memory.
__global__ __launch_bounds__(256) void k_g(const float* __restrict__ D,
                                           float* __restrict__ G,
                                           float* __restrict__ DnT,
                                           float* __restrict__ pd,
                                           float* __restrict__ Dnr,
                                           float* __restrict__ W) {
  __shared__ float Xs[64 * 64];
  __shared__ float Dns[64 * 64];
  __shared__ float partA[4][64];
  __shared__ float partB[4][64];
  __shared__ float invA[64];
  __shared__ float invB[64];
  int tid = threadIdx.x;
  int w = tid & 63, cq = tid >> 6;
  int ty = tid >> 4, tx = tid & 15;
  if (blockIdx.x == 0 && tid < 16) ((unsigned int*)W)[tid] = 0u;  // accs+hist zero

  int ti = (int)blockIdx.x >> 3, tj = (int)blockIdx.x & 7;
#pragma unroll
  for (int p = 0; p < 16; ++p) {
    int c = p * 4 + cq;
    Xs[c * 64 + w] = D[(size_t)c * KDIM + ti * 64 + w];
    Dns[c * 64 + w] = D[(size_t)c * KDIM + tj * 64 + w];
  }
  __syncthreads();
  float ssA = 0.f, ssB = 0.f;
#pragma unroll
  for (int cc = 0; cc < 16; ++cc) {
    int c = cq * 16 + cc;
    float a = Xs[c * 64 + w];
    ssA = fmaf(a, a, ssA);
    float bv = Dns[c * 64 + w];
    ssB = fmaf(bv, bv, ssB);
  }
  partA[cq][w] = ssA;
  partB[cq][w] = ssB;
  __syncthreads();
  if (tid < 64) {
    invA[tid] = 1.0f / sqrtf(partA[0][tid] + partA[1][tid] + partA[2][tid] + partA[3][tid]);
    invB[tid] = 1.0f / sqrtf(partB[0][tid] + partB[1][tid] + partB[2][tid] + partB[3][tid]);
  }
  __syncthreads();
  if (ti == tj) {
    // emit normalized DnT rows, Dnr slice, pd[ti] = sum|Dn| partial
    int kl = tid >> 2, cp = (tid & 3) * 16;
    float ia = invA[kl];
    int kg = ti * 64 + kl;              // global atom index
    float sabs = 0.f;
#pragma unroll
    for (int i = 0; i < 16; ++i) {
      int c = cp + i;
      float v = Xs[c * 64 + kl] * ia;
      DnT[(size_t)kg * CDIM + c] = v;
      Dnr[(size_t)c * KDIM + kg] = v;
      sabs += fabsf(v);
    }
#pragma unroll
    for (int off = 32; off >= 1; off >>= 1) sabs += __shfl_xor(sabs, off);
    __syncthreads();
    if ((tid & 63) == 0) partA[0][tid >> 6] = sabs;
    __syncthreads();
    if (tid == 0) pd[ti] = partA[0][0] + partA[0][1] + partA[0][2] + partA[0][3];
  }
  v2f acc[4][2] = {};
  for (int c = 0; c < 64; ++c) {
    float4 avv = *(const float4*)&Xs[c * 64 + ty * 4];
    float av[4] = {avv.x, avv.y, avv.z, avv.w};
    float4 bv = *(const float4*)&Dns[c * 64 + tx * 4];
    v2f b0 = {bv.x, bv.y}, b1 = {bv.z, bv.w};
#pragma unroll
    for (int i = 0; i < 4; ++i) {
      v2f a2 = {av[i], av[i]};
      acc[i][0] = __builtin_elementwise_fma(a2, b0, acc[i][0]);
      acc[i][1] = __builtin_elementwise_fma(a2, b1, acc[i][1]);
    }
  }
  float sn[4] = {invB[tx * 4], invB[tx * 4 + 1], invB[tx * 4 + 2], invB[tx * 4 + 3]};
#pragma unroll
  for (int i = 0; i < 4; ++i) {
    float im = invA[ty * 4 + i];
    float4 st = make_float4(acc[i][0].x * im * sn[0], acc[i][0].y * im * sn[1],
                            acc[i][1].x * im * sn[2], acc[i][1].y * im * sn[3]);
    *(float4*)&G[(size_t)(ti * 64 + ty * 4 + i) * KDIM + tj * 64 + tx * 4] = st;
  }
}

// ---- DPP wave-64 max of a non-negative float; returns wave-uniform (SGPR) value ----
__device__ __forceinline__ float wave_absmax_u(float m) {
#define DPP_MAX(ctrl)                                                              \
  {                                                                                \
    int t_ = __builtin_amdgcn_update_dpp(0, __float_as_int(m), (ctrl), 0xf, 0xf,   \
                                         true);                                    \
    m = fmaxf(m, __int_as_float(t_));                                              \
  }
  DPP_MAX(0x111) DPP_MAX(0x112) DPP_MAX(0x114) DPP_MAX(0x118)
  DPP_MAX(0x142) DPP_MAX(0x143)
#undef DPP_MAX
  return __int_as_float(__builtin_amdgcn_readlane(__float_as_int(m), 63));
}

// ---- fp32 solve, no pivoting (G_II near-identity), saved reciprocals ----
template <int SZ>
__device__ __forceinline__ void solve_sz(const float (&gs)[4][4], const float (&rhs)[4],
                                         float (&gamma)[4]) {
  float M[SZ][SZ];
  float y[SZ];
  float idg[SZ];
#pragma unroll
  for (int a = 0; a < SZ; ++a) {
    y[a] = rhs[a];
#pragma unroll
    for (int b = 0; b < SZ; ++b) M[a][b] = gs[a][b] + (a == b ? 1e-7f : 0.0f);
  }
#pragma unroll
  for (int p = 0; p < SZ; ++p) {
    float ip = __builtin_amdgcn_rcpf(M[p][p]);
    idg[p] = ip;
#pragma unroll
    for (int r = p + 1; r < SZ; ++r) {
      float f = M[r][p] * ip;
#pragma unroll
      for (int c = p + 1; c < SZ; ++c) M[r][c] = fmaf(-f, M[p][c], M[r][c]);
      y[r] = fmaf(-f, y[p], y[r]);
    }
  }
#pragma unroll
  for (int r = SZ - 1; r >= 0; --r) {
    float t = y[r];
#pragma unroll
    for (int c = r + 1; c < SZ; ++c) t = fmaf(-M[r][c], gamma[c], t);
    gamma[r] = t * idg[r];
  }
}

// ---- one OMP step; alpha parked in LDS (as_row = AS + sb*512).
// lane l owns atoms l*8..l*8+8 of the residual al.
template <int K>
__device__ __forceinline__ void omp_step3(int lane, const float* __restrict__ G,
                                          const float* as_row,
                                          float (&al)[8], float (&Grow)[3][8],
                                          float (&gs)[4][4], float (&rhs)[4],
                                          int (&idx)[4], float (&gamma)[4]) {
  // per-lane argmax with lowest-m tie-break (strict >)
  float mx0 = fabsf(al[0]);
  int mi = 0;
#pragma unroll
  for (int m = 1; m < 8; ++m) {
    float v = fabsf(al[m]);
    mi = (v > mx0) ? m : mi;
    mx0 = fmaxf(v, mx0);
  }
  float mx = wave_absmax_u(mx0);  // wave-uniform SGPR
  // single ballot; lowest lane wins; lane-major ordering == reference argmax
  unsigned long long bm = __ballot(mx0 == mx);
  int wl = (int)__builtin_ctzll(bm);
  int mwin = __builtin_amdgcn_readlane(mi, wl);
  int sk = wl * 8 + mwin;  // wave-uniform
  idx[K] = sk;

  const float* grow_base = G + (size_t)sk * KDIM;
  // a0 reload for the residual update — issued early, independent of Grow
  float4 p0, p1;
  if constexpr (K < 3) {
    p0 = *(const float4*)&as_row[lane * 8];
    p1 = *(const float4*)&as_row[lane * 8 + 4];
  }
  if constexpr (K < 3) {
    const float4* gp = (const float4*)(grow_base + lane * 8);
    float4 r0 = gp[0], r1 = gp[1];
    Grow[K][0] = r0.x; Grow[K][1] = r0.y; Grow[K][2] = r0.z; Grow[K][3] = r0.w;
    Grow[K][4] = r1.x; Grow[K][5] = r1.y; Grow[K][6] = r1.z; Grow[K][7] = r1.w;
  }

#pragma unroll
  for (int b2 = 0; b2 < K; ++b2) {
    float v = grow_base[idx[b2]];
    gs[K][b2] = v;
    gs[b2][K] = v;
  }
  gs[K][K] = grow_base[sk];
  rhs[K] = as_row[sk];  // wave-uniform LDS scalar (parked alpha0)

  solve_sz<K + 1>(gs, rhs, gamma);

  if constexpr (K < 3) {
    float a0v[8] = {p0.x, p0.y, p0.z, p0.w, p1.x, p1.y, p1.z, p1.w};
#pragma unroll
    for (int m = 0; m < 8; ++m) {
      float acc2 = a0v[m];
#pragma unroll
      for (int a = 0; a <= K; ++a) acc2 = fmaf(-gamma[a], Grow[a][m], acc2);
      al[m] = acc2;
    }
  }
}

// ---- fused alpha0 + OMP: 2048 blocks x 4 waves; 16 signals per block.
// GEMM: wave w computes atoms [w*128, w*128+128) for ALL 16 block-signals
// (acc = 16 v2f), D streamed from L2 (32 KB/wave), X read via uniform-address
// float4 loads (L1 broadcast, zero LDS-port cost). Alpha parked in LDS
// (32 KB -> 4 blocks/CU with VGPR<=128), barrier, then each wave OMPs 4
// signals with alpha rows served from LDS.
__global__ __launch_bounds__(256, 4) void k_fused(const float* __restrict__ X,
                                                  const float* __restrict__ Dnr,
                                                  const float* __restrict__ G,
                                                  float4* __restrict__ wg,
                                                  int4* __restrict__ wi) {
  __shared__ __align__(16) float AS[16 * 512];  // alpha park: 16 signals (32 KB)
  int tid = threadIdx.x;
  int lane = tid & 63;
  int wv = __builtin_amdgcn_readfirstlane(tid >> 6);
  int bid = (int)blockIdx.x;
  int bh = bid >> 2, w0 = (bid & 3) * 16;  // bh = b*64+h
  int b = bh >> 6, h = bh & 63;

  // ---- GEMM: acc[sig] over this wave's 128-atom slice ----
  v2f acc[16] = {};
  const v2f* dp = (const v2f*)Dnr + wv * 64 + lane;  // + c*256 per row
  const float* xbase = X + ((size_t)b * CDIM * HQ + h) * WQ + w0;
#pragma unroll 4
  for (int c = 0; c < 64; ++c) {
    v2f d = dp[c * 256];                                   // 8B/lane, 512B/wave contig
    const float4* xp = (const float4*)(xbase + (size_t)c * (HQ * WQ));
    float4 x0 = xp[0], x1 = xp[1], x2 = xp[2], x3 = xp[3];  // uniform addr: L1 bcast
    float xv[16] = {x0.x, x0.y, x0.z, x0.w, x1.x, x1.y, x1.z, x1.w,
                    x2.x, x2.y, x2.z, x2.w, x3.x, x3.y, x3.z, x3.w};
#pragma unroll
    for (int s = 0; s < 16; ++s) {
      v2f xx = {xv[s], xv[s]};
      acc[s] = __builtin_elementwise_fma(xx, d, acc[s]);
    }
  }

  // ---- park alpha: AS[sig][atom], this wave fills atoms wv*128..+128 ----
#pragma unroll
  for (int s = 0; s < 16; ++s)
    *(v2f*)&AS[s * 512 + wv * 128 + lane * 2] = acc[s];
  __syncthreads();

  // ---- OMP: wave wv handles block-signals wv*4..wv*4+4 ----
#pragma unroll 1
  for (int s = 0; s < 4; ++s) {
    int sb = wv * 4 + s;
    int n = bid * 16 + sb;
    const float* as_row = &AS[sb * 512];
    float4 q0 = *(const float4*)&as_row[lane * 8];
    float4 q1 = *(const float4*)&as_row[lane * 8 + 4];
    float al[8] = {q0.x, q0.y, q0.z, q0.w, q1.x, q1.y, q1.z, q1.w};
    float Grow[3][8];
    float gs[4][4];
    float rhs[4];
    int idx[4];
    float gamma[4];
    omp_step3<0>(lane, G, as_row, al, Grow, gs, rhs, idx, gamma);
    omp_step3<1>(lane, G, as_row, al, Grow, gs, rhs, idx, gamma);
    omp_step3<2>(lane, G, as_row, al, Grow, gs, rhs, idx, gamma);
    omp_step3<3>(lane, G, as_row, al, Grow, gs, rhs, idx, gamma);
    // dedupe: scatter-set semantics — later slot with same index wins
    bool k0 = (idx[0] != idx[1]) && (idx[0] != idx[2]) && (idx[0] != idx[3]);
    bool k1 = (idx[1] != idx[2]) && (idx[1] != idx[3]);
    bool k2 = (idx[2] != idx[3]);
    if (lane == 0) {
      wg[n] = make_float4(k0 ? gamma[0] : 0.f, k1 ? gamma[1] : 0.f,
                          k2 ? gamma[2] : 0.f, gamma[3]);
      wi[n] = make_int4(idx[0], idx[1], idx[2], idx[3]);
    }
  }
}

// ---- fused epilogue: blocks 0..511 quant+stats, 512..2559 dense ids ----
__global__ __launch_bounds__(256) void k_ei(const float* __restrict__ X,
                                            const float* __restrict__ DnT,
                                            const float4* __restrict__ wg,
                                            const int4* __restrict__ wi,
                                            float* __restrict__ out,
                                            double* __restrict__ accs,
                                            int* __restrict__ hist) {
  __shared__ __align__(16) int sIdx[64][4];
  __shared__ __align__(16) float sKg[64][4];
  __shared__ float q[64 * 65];
  __shared__ float red[4];
  int tid = threadIdx.x;

  if (blockIdx.x < 512) {
    int bh = blockIdx.x;
    int b = bh >> 6, h = bh & 63;
    if (tid < 64) {
      int w = tid;
      int n = bh * 64 + w;
      int4 iv = wi[n];
      float4 gv = wg[n];  // already deduped in k_fused
      sIdx[w][0] = iv.x; sIdx[w][1] = iv.y; sIdx[w][2] = iv.z; sIdx[w][3] = iv.w;
      sKg[w][0] = gv.x; sKg[w][1] = gv.y; sKg[w][2] = gv.z; sKg[w][3] = gv.w;
      int nz = (int)(gv.x != 0.f) + (int)(gv.y != 0.f) +
               (int)(gv.z != 0.f) + (int)(gv.w != 0.f);
      float s = fabsf(gv.x) + fabsf(gv.y) + fabsf(gv.z) + fabsf(gv.w);
#pragma unroll
      for (int off = 32; off >= 1; off >>= 1) s += __shfl_xor(s, off);
#pragma unroll
      for (int v = 0; v < 5; ++v) {
        unsigned long long m = __ballot(nz == v);
        if (tid == 0) {
          int c = (int)__popcll(m);
          if (c) atomicAdd(&hist[v], c);
        }
      }
      if (tid == 0) atomicAdd(&accs[0], (double)s);
    }
    __syncthreads();

    int w2 = tid & 63, p = tid >> 6, c0 = p * 16;
    float acc[16] = {};
#pragma unroll
    for (int s = 0; s < 4; ++s) {
      int ks = sIdx[w2][s];
      float g = sKg[w2][s];
      const float4* dp = (const float4*)(DnT + (size_t)ks * CDIM + c0);
#pragma unroll
      for (int i4 = 0; i4 < 4; ++i4) {
        float4 d = dp[i4];
        acc[i4 * 4 + 0] = fmaf(g, d.x, acc[i4 * 4 + 0]);
        acc[i4 * 4 + 1] = fmaf(g, d.y, acc[i4 * 4 + 1]);
        acc[i4 * 4 + 2] = fmaf(g, d.z, acc[i4 * 4 + 2]);
        acc[i4 * 4 + 3] = fmaf(g, d.w, acc[i4 * 4 + 3]);
      }
    }
#pragma unroll
    for (int i = 0; i < 16; ++i) q[(c0 + i) * 65 + w2] = acc[i];
    __syncthreads();

    float sumsq = 0.f;
#pragma unroll
    for (int pass = 0; pass < 16; ++pass) {
      int c = pass * 4 + p;
      float qv = q[c * 65 + w2];
      size_t off = (((size_t)b * CDIM + c) * HQ + h) * WQ + w2;
      float xv = X[off];
      float d = qv - xv;
      sumsq = fmaf(d, d, sumsq);
      out[off] = qv;
    }

#pragma unroll
    for (int off = 32; off >= 1; off >>= 1) sumsq += __shfl_xor(sumsq, off);
    if ((tid & 63) == 0) red[tid >> 6] = sumsq;
    __syncthreads();
    if (tid == 0) atomicAdd(&accs[1], (double)(red[0] + red[1] + red[2] + red[3]));
  } else {
    // ---------------- dense ids write (dwordx4, 4 signals/thread) ----------------
    int bid = blockIdx.x - 512;
    int bh = bid >> 2, kq = bid & 3;
    int b = bh >> 6, h = bh & 63;
    if (tid < 64) {
      int n = bh * 64 + tid;
      *(int4*)&sIdx[tid][0] = wi[n];
      *(float4*)&sKg[tid][0] = wg[n];
    }
    __syncthreads();
    int w4 = (tid & 15) * 4, kl = tid >> 4;
    int4 I0 = *(const int4*)&sIdx[w4][0];
    int4 I1 = *(const int4*)&sIdx[w4 + 1][0];
    int4 I2 = *(const int4*)&sIdx[w4 + 2][0];
    int4 I3 = *(const int4*)&sIdx[w4 + 3][0];
    float4 G0 = *(const float4*)&sKg[w4][0];
    float4 G1 = *(const float4*)&sKg[w4 + 1][0];
    float4 G2 = *(const float4*)&sKg[w4 + 2][0];
    float4 G3 = *(const float4*)&sKg[w4 + 3][0];
    float* ids = out + IDS_OFF;
    size_t base = (((size_t)b * KDIM + kq * 128 + kl) * HQ + h) * WQ + w4;
#pragma unroll
    for (int pass = 0; pass < 8; ++pass) {
      int k = kq * 128 + pass * 16 + kl;
      // reverse-order select chain = scatter last-wins semantics
      float4 v;
      v.x = (k == I0.w) ? G0.w : (k == I0.z) ? G0.z : (k == I0.y) ? G0.y : (k == I0.x) ? G0.x : 0.f;
      v.y = (k == I1.w) ? G1.w : (k == I1.z) ? G1.z : (k == I1.y) ? G1.y : (k == I1.x) ? G1.x : 0.f;
      v.z = (k == I2.w) ? G2.w : (k == I2.z) ? G2.z : (k == I2.y) ? G2.y : (k == I2.x) ? G2.x : 0.f;
      v.w = (k == I3.w) ? G3.w : (k == I3.z) ? G3.z : (k == I3.y) ? G3.y : (k == I3.x) ? G3.x : 0.f;
      *(float4*)&ids[base + (size_t)pass * 16 * 4096] = v;
    }
  }
}

// ---- finalize scalars (separate 1-block dispatch; stream order = no fence needed) ----
__global__ __launch_bounds__(64) void k_final(const double* __restrict__ accs,
                                              const int* __restrict__ hist,
                                              const float* __restrict__ pd,
                                              float* __restrict__ out) {
  if (threadIdx.x == 0) {
    float sumAbsD = 0.f;
#pragma unroll
    for (int i = 0; i < 8; ++i) sumAbsD += pd[i];
    double sumAbsZ = accs[0], sumSq = accs[1];
    float diff = (float)(sumSq / 2097152.0);
    out[DIFF_ENC_OFF] = diff;
    out[DIFF_DICT_OFF] = diff;
    out[NUM_STEPS_OFF] = 4.0f;
    out[MEAN_D_OFF] = sumAbsD / 32768.0f;
    out[MEAN_Z_OFF] = (float)(sumAbsZ / 16777216.0);
    int h0 = hist[0], h1 = hist[1], h2 = hist[2], h3 = hist[3], h4 = hist[4];
    out[NORM_Z_OFF] = (float)((double)(h1 + 2 * h2 + 3 * h3 + 4 * h4) / 32768.0);
    int cum = 0, res = 0;
    for (int v = 4; v >= 0; --v) {
      cum += hist[v];
      if (cum >= 327) { res = v; break; }
    }
    out[TOP_PCT_OFF] = (float)res;
    out[NUM_ZEROS_OFF] = (float)h0;
  }
}

extern "C" void kernel_launch(void* const* d_in, const int* in_sizes, int n_in,
                              void* d_out, int out_size, void* d_ws, size_t ws_size,
                              hipStream_t stream) {
  (void)in_sizes; (void)n_in; (void)out_size; (void)ws_size;
  const float* X = (const float*)d_in[0];    // [8,64,64,64]
  const float* D = (const float*)d_in[1];    // [64,512]
  float* out = (float*)d_out;
  float* W = (float*)d_ws;
  double* accs = (double*)d_ws;
  int* hist = (int*)W + 4;
  float* pd = W + WS_PD;
  float* DnT = W + WS_DNT;
  float* G = W + WS_G;
  float4* wgam = (float4*)(W + WS_WG);
  int4* widx = (int4*)(W + WS_WI);
  float* Dnr = out + DNR_OFF;  // staged in ids region; k_ei overwrites later

  hipLaunchKernelGGL(k_g, dim3(64), dim3(256), 0, stream, D, G, DnT, pd, Dnr, W);
  hipLaunchKernelGGL(k_fused, dim3(2048), dim3(256), 0, stream, X, Dnr, G, wgam, widx);
  hipLaunchKernelGGL(k_ei, dim3(2560), dim3(256), 0, stream, X, DnT, wgam, widx, out, accs, hist);
  hipLaunchKernelGGL(k_final, dim3(1), dim3(64), 0, stream, accs, hist, pd, out);
}